// Round 10
// baseline (848.973 us; speedup 1.0000x reference)
//
#include <hip/hip_runtime.h>
#include <hip/hip_bf16.h>
#include <stdint.h>

#define TTOK 2048
#define DDIM 2048
#define IDIM 5632
#define NEXP 8

typedef __attribute__((ext_vector_type(8))) short bf16x8;
typedef __attribute__((ext_vector_type(4))) float f32x4;
typedef __attribute__((ext_vector_type(8))) unsigned short u16x8;
typedef __attribute__((ext_vector_type(4))) unsigned short u16x4;

__device__ __forceinline__ unsigned short f2bf(float f) {
  union { float f; uint32_t u; } v; v.f = f;
  uint32_t u = v.u + 0x7fffu + ((v.u >> 16) & 1u);
  return (unsigned short)(u >> 16);
}

__device__ __forceinline__ uint32_t fbits(float f) {
  union { float f; uint32_t u; } v; v.f = f; return v.u;
}

// truncating packed f32x2 -> bf16x2 via v_perm_b32 (1 inst per 2 values)
__device__ __forceinline__ u16x8 cvt8t(float4 a, float4 b) {
  union { u16x8 v; uint32_t w[4]; } r;
  r.w[0] = __builtin_amdgcn_perm(fbits(a.y), fbits(a.x), 0x07060302);
  r.w[1] = __builtin_amdgcn_perm(fbits(a.w), fbits(a.z), 0x07060302);
  r.w[2] = __builtin_amdgcn_perm(fbits(b.y), fbits(b.x), 0x07060302);
  r.w[3] = __builtin_amdgcn_perm(fbits(b.w), fbits(b.z), 0x07060302);
  return r.v;
}

typedef __attribute__((address_space(3))) void lds_t;
typedef const __attribute__((address_space(1))) void gbl_t;
__device__ __forceinline__ void gload16(const void* g, void* l) {
  __builtin_amdgcn_global_load_lds((gbl_t*)g, (lds_t*)l, 16, 0, 0);
}

// single barrier per K-step: retire this iter's A-gloads (oldest), keep the
// 4 B reg-loads (next-next tile) in flight; drain lgkm for ds_write publish.
#define PIPE_BAR() asm volatile("s_waitcnt vmcnt(4) lgkmcnt(0)\n\ts_barrier" ::: "memory")

// ---------------- router: logits, top-2, softmax, expert lists ----------------
__global__ __launch_bounds__(256) void router_kernel(
    const float* __restrict__ x, const float* __restrict__ gw,
    int* __restrict__ cnt, int* __restrict__ slots, float* __restrict__ wts)
{
  const int lane = threadIdx.x & 63;
  const int t = (blockIdx.x * blockDim.x + threadIdx.x) >> 6;  // one wave per token
  const float* xr = x + (size_t)t * DDIM;
  float acc[NEXP];
#pragma unroll
  for (int e = 0; e < NEXP; ++e) acc[e] = 0.f;
#pragma unroll
  for (int it = 0; it < DDIM / 256; ++it) {
    const int d = (it * 64 + lane) * 4;
    const float4 xv = *(const float4*)(xr + d);
#pragma unroll
    for (int e = 0; e < NEXP; ++e) {
      const float4 gv = *(const float4*)(gw + (size_t)e * DDIM + d);
      acc[e] += xv.x*gv.x + xv.y*gv.y + xv.z*gv.z + xv.w*gv.w;
    }
  }
#pragma unroll
  for (int e = 0; e < NEXP; ++e) {
    float v = acc[e];
#pragma unroll
    for (int off = 32; off > 0; off >>= 1) v += __shfl_xor(v, off);
    acc[e] = v;
  }
  if (lane == 0) {
    int i0 = 0; float v0 = acc[0];
#pragma unroll
    for (int e = 1; e < NEXP; ++e) if (acc[e] > v0) { v0 = acc[e]; i0 = e; }
    int i1 = -1; float v1 = -3.4e38f;
#pragma unroll
    for (int e = 0; e < NEXP; ++e) { if (e == i0) continue; if (acc[e] > v1) { v1 = acc[e]; i1 = e; } }
    const float e1 = __expf(v1 - v0);
    const float w0 = 1.f / (1.f + e1);
    const float w1 = e1 / (1.f + e1);
    const int p0 = atomicAdd(&cnt[i0], 1);
    slots[i0 * TTOK + p0] = t * 2;     wts[i0 * TTOK + p0] = w0;
    const int p1 = atomicAdd(&cnt[i1], 1);
    slots[i1 * TTOK + p1] = t * 2 + 1; wts[i1 * TTOK + p1] = w1;
  }
}

// ---------------- plan: padded prefix offsets + compact tile list ----------------
__global__ void plan_kernel(const int* __restrict__ cnt,
                            int* __restrict__ tilemap, int* __restrict__ ntiles,
                            int* __restrict__ po)
{
  if (threadIdx.x == 0 && blockIdx.x == 0) {
    int n = 0, off = 0;
#pragma unroll
    for (int e = 0; e < NEXP; ++e) {
      po[e] = off;
      const int nt = (cnt[e] + 127) >> 7;
      for (int m = 0; m < nt; ++m) tilemap[n++] = (e << 8) | m;
      off += nt << 7;
    }
    ntiles[0] = n;   // <= 40
  }
}

// ---------------- pack: gather routed token rows -> contiguous per-expert bf16 A ----------------
__global__ __launch_bounds__(256) void pack_kernel(
    const float* __restrict__ x, const int* __restrict__ cnt,
    const int* __restrict__ slots, const int* __restrict__ po,
    unsigned short* __restrict__ xs)
{
  const int e = blockIdx.x >> 9;                        // 8 x 512 blocks
  const int count = cnt[e];
  const int padded = (count + 127) & ~127;
  const int rr = (blockIdx.x & 511) * 4 + (threadIdx.x >> 6);  // 4 rows/block
  if (rr >= padded) return;
  const int lane = threadIdx.x & 63;
  unsigned short* dst = xs + (size_t)(po[e] + rr) * DDIM;
  if (rr < count) {
    const float* src = x + (size_t)(slots[e * TTOK + rr] >> 1) * DDIM;
#pragma unroll
    for (int i = 0; i < 8; ++i) {
      const int d = (i * 64 + lane) * 4;
      const float4 v = *(const float4*)(src + d);
      u16x4 b; b[0]=f2bf(v.x); b[1]=f2bf(v.y); b[2]=f2bf(v.z); b[3]=f2bf(v.w);
      *(u16x4*)(dst + d) = b;
    }
  } else {
    const u16x4 z = {};
#pragma unroll
    for (int i = 0; i < 8; ++i) *(u16x4*)(dst + (i * 64 + lane) * 4) = z;
  }
}

// chunk swizzle: 16B chunk c of row r stored at chunk c ^ (r & 7)

// ---- gate+up grouped GEMM: 128M x 64N, g/u wave-split, linear packed A ----
__global__ __launch_bounds__(512, 4) void gateup_kernel(
    const unsigned short* __restrict__ xs,
    const float* __restrict__ wg, const float* __restrict__ wu,
    const int* __restrict__ cnt, const int* __restrict__ po,
    const int* __restrict__ tilemap, const int* __restrict__ ntiles,
    unsigned short* __restrict__ h)
{
  // grid 3520 = 40 tile-slots x 88 n-panels; XCD swizzle (q=440), tile fastest
  const int flat = (blockIdx.x & 7) * 440 + (blockIdx.x >> 3);
  const int ti = flat % 40;
  if (ti >= ntiles[0]) return;
  const int em = tilemap[ti];
  const int e = em >> 8;
  const int mt = em & 255;
  const int n0 = (flat / 40) * 64;
  const int count = cnt[e];
  const int m0 = mt * 128;
  const int abase = po[e] + m0;      // packed row base (128-aligned)

  __shared__ unsigned short A[2][128][64];    // 32 KB (reused as fp32 u-exchange)
  __shared__ unsigned short Bg[2][64][64];    // 16 KB
  __shared__ unsigned short Bu[2][64][64];    // 16 KB

  const int tid = threadIdx.x;
  const int lane = tid & 63;
  const int wid = tid >> 6;

  // A staging: linear rows, chunk pre-swizzled within row
  const int aswz = ((lane & 7) ^ ((lane >> 3) & 7)) * 8;
  const unsigned short* aptr[2];
#pragma unroll
  for (int j = 0; j < 2; ++j) {
    const int arow = wid * 16 + j * 8 + (lane >> 3);
    aptr[j] = xs + (size_t)(abase + arow) * DDIM + aswz;
  }

  // wave role: waves 0-3 = gate, 4-7 = up
  const int mat = wid >> 2;
  unsigned short (*Bm)[64][64] = (mat == 0) ? Bg : Bu;
  const float* wsel = (mat == 0) ? wg : wu;

  const int tidm = tid & 255;
  const int brow = tidm >> 2;
  const int bcb = (tidm & 3) * 2;
  const int bswz = brow & 7;
  const float* msrc = wsel + (size_t)e * IDIM * DDIM + (size_t)(n0 + brow) * DDIM + bcb * 8;

  const int wr = (wid >> 1) & 1, wc = wid & 1;
  const int fr = lane & 15;
  const int kc = lane >> 4;
  const int rsw = fr & 7;

  f32x4 acc[4][2] = {};

  float4 P[4];
  // prologue: A(0)->bufA[0]; B(0)->regs->bufB[0]; B(1)->regs
#pragma unroll
  for (int j = 0; j < 2; ++j) gload16(aptr[j], &A[0][wid * 16][0] + j * 512);
#pragma unroll
  for (int q = 0; q < 4; ++q) P[q] = *(const float4*)(msrc + q * 4);
#pragma unroll
  for (int qq = 0; qq < 2; ++qq)
    *(u16x8*)&Bm[0][brow][((bcb + qq) ^ bswz) * 8] = cvt8t(P[qq * 2], P[qq * 2 + 1]);
#pragma unroll
  for (int q = 0; q < 4; ++q) P[q] = *(const float4*)(msrc + 64 + q * 4);
  PIPE_BAR();

#pragma unroll 2
  for (int t = 0; t < 32; ++t) {
    const int cur = t & 1;
    const int kp  = (t + 1 <= 31) ? (t + 1) * 64 : 31 * 64;
    const int kp2 = (t + 2 <= 31) ? (t + 2) * 64 : 31 * 64;

    // 1) A(t+1) direct-to-LDS (stays oldest vmem of this iter)
#pragma unroll
    for (int j = 0; j < 2; ++j) gload16(aptr[j] + kp, &A[cur ^ 1][wid * 16][0] + j * 512);
    __builtin_amdgcn_sched_barrier(0);
    // 2) cvt + ds_write B(t+1); 3) B(t+2) -> regs
#pragma unroll
    for (int qq = 0; qq < 2; ++qq)
      *(u16x8*)&Bm[cur ^ 1][brow][((bcb + qq) ^ bswz) * 8] = cvt8t(P[qq * 2], P[qq * 2 + 1]);
#pragma unroll
    for (int q = 0; q < 4; ++q) P[q] = *(const float4*)(msrc + kp2 + q * 4);
    __builtin_amdgcn_sched_barrier(0);

    // 4) MFMA on buf[cur]
#pragma unroll
    for (int kk = 0; kk < 2; ++kk) {
      bf16x8 a[4], b[2];
      const int cs = ((kk * 4 + kc) ^ rsw) * 8;
#pragma unroll
      for (int mf = 0; mf < 4; ++mf)
        a[mf] = *(const bf16x8*)&A[cur][wr * 64 + mf * 16 + fr][cs];
#pragma unroll
      for (int nf = 0; nf < 2; ++nf)
        b[nf] = *(const bf16x8*)&Bm[cur][wc * 32 + nf * 16 + fr][cs];
#pragma unroll
      for (int mf = 0; mf < 4; ++mf)
#pragma unroll
        for (int nf = 0; nf < 2; ++nf)
          acc[mf][nf] = __builtin_amdgcn_mfma_f32_16x16x32_bf16(a[mf], b[nf], acc[mf][nf], 0, 0, 0);
    }

    // 5) publish buf[cur^1]
    PIPE_BAR();
  }

  // epilogue: u-waves export via LDS (overlay dead A buffer), g-waves fuse SiLU
  __syncthreads();
  float* uex = (float*)&A[0][0][0];   // [128][64] fp32
  if (mat == 1) {
#pragma unroll
    for (int mf = 0; mf < 4; ++mf)
#pragma unroll
      for (int nf = 0; nf < 2; ++nf)
#pragma unroll
        for (int j = 0; j < 4; ++j) {
          const int r = wr * 64 + mf * 16 + (lane >> 4) * 4 + j;
          const int c = wc * 32 + nf * 16 + fr;
          uex[r * 64 + c] = acc[mf][nf][j];
        }
  }
  __syncthreads();
  if (mat == 0) {
#pragma unroll
    for (int mf = 0; mf < 4; ++mf)
#pragma unroll
      for (int nf = 0; nf < 2; ++nf)
#pragma unroll
        for (int j = 0; j < 4; ++j) {
          const int r = wr * 64 + mf * 16 + (lane >> 4) * 4 + j;
          const int c = wc * 32 + nf * 16 + fr;
          if (m0 + r < count) {
            const float g = acc[mf][nf][j];
            const float u = uex[r * 64 + c];
            const float hv = g / (1.f + __expf(-g)) * u;
            h[(size_t)(abase + r) * IDIM + n0 + c] = f2bf(hv);
          }
        }
  }
}

// ---- down grouped GEMM: 128M x 64N, K-split x2, linear packed A, scatter epilogue ----
__global__ __launch_bounds__(256, 4) void down_kernel(
    const unsigned short* __restrict__ h,
    const float* __restrict__ wd,
    const int* __restrict__ cnt, const int* __restrict__ slots,
    const float* __restrict__ wts, const int* __restrict__ po,
    const int* __restrict__ tilemap, const int* __restrict__ ntiles,
    float* __restrict__ out)
{
  // grid 2560 = 40 tile-slots x 32 n-panels x 2 k-splits; XCD swizzle (q=320)
  const int flat = (blockIdx.x & 7) * 320 + (blockIdx.x >> 3);
  const int ti = flat % 40;
  if (ti >= ntiles[0]) return;
  const int em = tilemap[ti];
  const int e = em >> 8;
  const int mt = em & 255;
  const int rest = flat / 40;          // 0..63
  const int n0 = (rest & 31) * 64;
  const int kbase = (rest >> 5) * (IDIM / 2);
  const int count = cnt[e];
  const int m0 = mt * 128;
  const int abase = po[e] + m0;

  __shared__ unsigned short A[2][128][64];   // 32 KB
  __shared__ unsigned short B[2][64][64];    // 16 KB
  __shared__ int rtok[128];
  __shared__ float rw[128];

  const int tid = threadIdx.x;
  const int lane = tid & 63;
  const int wid = tid >> 6;

  if (tid < 128) {
    const int idx = m0 + tid;
    rtok[tid] = (idx < count) ? (slots[e * TTOK + idx] >> 1) : 0;
    rw[tid] = (idx < count) ? wts[e * TTOK + idx] : 0.f;
  }

  const int aswz = ((lane & 7) ^ ((lane >> 3) & 7)) * 8;
  const unsigned short* aptr[4];
#pragma unroll
  for (int j = 0; j < 4; ++j) {
    const int arow = wid * 32 + j * 8 + (lane >> 3);
    aptr[j] = h + (size_t)(abase + arow) * IDIM + kbase + aswz;
  }

  const int brow = tid >> 2;
  const int bcb = (tid & 3) * 2;
  const int bswz = brow & 7;
  const float* bsrc = wd + (size_t)e * DDIM * IDIM + (size_t)(n0 + brow) * IDIM + kbase + bcb * 8;

  const int wr = wid >> 1, wc = wid & 1;
  const int fr = lane & 15;
  const int kc = lane >> 4;
  const int rsw = fr & 7;

  f32x4 acc[4][2] = {};

  float4 P[4];
  // prologue
#pragma unroll
  for (int j = 0; j < 4; ++j) gload16(aptr[j], &A[0][wid * 32][0] + j * 512);
#pragma unroll
  for (int q = 0; q < 4; ++q) P[q] = *(const float4*)(bsrc + q * 4);
#pragma unroll
  for (int qq = 0; qq < 2; ++qq)
    *(u16x8*)&B[0][brow][((bcb + qq) ^ bswz) * 8] = cvt8t(P[qq * 2], P[qq * 2 + 1]);
#pragma unroll
  for (int q = 0; q < 4; ++q) P[q] = *(const float4*)(bsrc + 64 + q * 4);
  PIPE_BAR();

#pragma unroll 2
  for (int t = 0; t < 44; ++t) {
    const int cur = t & 1;
    const int kp  = (t + 1 <= 43) ? (t + 1) * 64 : 43 * 64;
    const int kp2 = (t + 2 <= 43) ? (t + 2) * 64 : 43 * 64;

#pragma unroll
    for (int j = 0; j < 4; ++j) gload16(aptr[j] + kp, &A[cur ^ 1][wid * 32][0] + j * 512);
    __builtin_amdgcn_sched_barrier(0);
#pragma unroll
    for (int qq = 0; qq < 2; ++qq)
      *(u16x8*)&B[cur ^ 1][brow][((bcb + qq) ^ bswz) * 8] = cvt8t(P[qq * 2], P[qq * 2 + 1]);
#pragma unroll
    for (int q = 0; q < 4; ++q) P[q] = *(const float4*)(bsrc + kp2 + q * 4);
    __builtin_amdgcn_sched_barrier(0);

#pragma unroll
    for (int kk = 0; kk < 2; ++kk) {
      bf16x8 a[4], b[2];
      const int cs = ((kk * 4 + kc) ^ rsw) * 8;
#pragma unroll
      for (int mf = 0; mf < 4; ++mf)
        a[mf] = *(const bf16x8*)&A[cur][wr * 64 + mf * 16 + fr][cs];
#pragma unroll
      for (int nf = 0; nf < 2; ++nf)
        b[nf] = *(const bf16x8*)&B[cur][wc * 32 + nf * 16 + fr][cs];
#pragma unroll
      for (int mf = 0; mf < 4; ++mf)
#pragma unroll
        for (int nf = 0; nf < 2; ++nf)
          acc[mf][nf] = __builtin_amdgcn_mfma_f32_16x16x32_bf16(a[mf], b[nf], acc[mf][nf], 0, 0, 0);
    }

    PIPE_BAR();
  }

#pragma unroll
  for (int mf = 0; mf < 4; ++mf)
#pragma unroll
    for (int j = 0; j < 4; ++j) {
      const int r = wr * 64 + mf * 16 + (lane >> 4) * 4 + j;
      if (m0 + r < count) {
        const int t2 = rtok[r];
        const float w = rw[r];
#pragma unroll
        for (int nf = 0; nf < 2; ++nf)
          atomicAdd(out + (size_t)t2 * DDIM + n0 + wc * 32 + nf * 16 + fr,
                    acc[mf][nf][j] * w);
      }
    }
}

extern "C" void kernel_launch(void* const* d_in, const int* in_sizes, int n_in,
                              void* d_out, int out_size, void* d_ws, size_t ws_size,
                              hipStream_t stream) {
  const float* x  = (const float*)d_in[0];
  const float* gw = (const float*)d_in[1];
  const float* wg = (const float*)d_in[2];
  const float* wu = (const float*)d_in[3];
  const float* wd = (const float*)d_in[4];
  float* out = (float*)d_out;

  // packed capacity: 4096 real rows + <=8*127 padding -> 5120 rows
  char* ws = (char*)d_ws;
  unsigned short* xs = (unsigned short*)ws;                        // 5120*2048*2 = 20,971,520 B
  unsigned short* h  = (unsigned short*)(ws + 20971520);           // 5120*5632*2 = 57,671,680 B
  int*   slots = (int*)(ws + 78643200);                            // 65,536 B
  float* wts   = (float*)(ws + 78708736);                          // 65,536 B
  int*   cnt   = (int*)(ws + 78774272);                            // 32 B
  int*   tmap  = (int*)(ws + 78774304);                            // 256 B
  int*   ntl   = (int*)(ws + 78774560);                            // 4 B
  int*   po    = (int*)(ws + 78774564);                            // 32 B

  hipMemsetAsync(cnt, 0, NEXP * sizeof(int), stream);
  hipMemsetAsync(d_out, 0, (size_t)TTOK * DDIM * sizeof(float), stream);

  router_kernel<<<TTOK / 4, 256, 0, stream>>>(x, gw, cnt, slots, wts);
  plan_kernel<<<1, 64, 0, stream>>>(cnt, tmap, ntl, po);
  pack_kernel<<<NEXP * 512, 256, 0, stream>>>(x, cnt, slots, po, xs);
  gateup_kernel<<<3520, 512, 0, stream>>>(xs, wg, wu, cnt, po, tmap, ntl, h);
  down_kernel<<<2560, 256, 0, stream>>>(h, wd, cnt, slots, wts, po, tmap, ntl, out);
}